// Round 8
// baseline (114.777 us; speedup 1.0000x reference)
//
#include <hip/hip_runtime.h>

// Involution: B=4, C=256, H=W=56, K=7, GC=16 -> G=16, Cr=64, K2=49
// R8: SINGLE kernel, grid 196 = (49 tiles x 4 b), 256 threads, all blocks
//     co-resident (1/CU). conv1 computed ONCE per tile (zero redundancy,
//     zero mid HBM traffic, no k1 dispatch), then serial loop over all 16
//     groups: conv2 GEMM -> lw2 f32; halo f16 -> lxh; fp32-accum apply.
//     halo(g+1)+cw(g+1) prefetched into regs during apply(g).
//     Bijective XCD chunking (q=24,r=4) over wg=(b,tile) for halo L2 reuse.
// LDS map (R6's, verified):
//   [0, 9216)       bufA [64px][72] f16   - conv1 x-chunk staging
//   [0, 8960)       lxh  [16ch][14][20] f16 halo - overlays bufA after conv1
//   [9216, 18432)   lmid [64px][72] f16   - conv1 output tile (persistent)
//   [18432, 31760)  lw2  [49][68]   f32   - generated weights (per g)
// ws unused.

#define EPS 1e-5f

typedef __fp16 half2t __attribute__((ext_vector_type(2)));
typedef __fp16 half4t __attribute__((ext_vector_type(4)));
typedef __fp16 half8t __attribute__((ext_vector_type(8)));
typedef float floatx4 __attribute__((ext_vector_type(4)));

__device__ inline half8t pack8(float4 u0, float4 u1, float s) {
    half8t a;
    half2t q;
    q = __builtin_amdgcn_cvt_pkrtz(u0.x * s, u0.y * s); a[0] = q[0]; a[1] = q[1];
    q = __builtin_amdgcn_cvt_pkrtz(u0.z * s, u0.w * s); a[2] = q[0]; a[3] = q[1];
    q = __builtin_amdgcn_cvt_pkrtz(u1.x * s, u1.y * s); a[4] = q[0]; a[5] = q[1];
    q = __builtin_amdgcn_cvt_pkrtz(u1.z * s, u1.w * s); a[6] = q[0]; a[7] = q[1];
    return a;
}

__global__ __launch_bounds__(256, 2) void k_fused(
    const float* __restrict__ x, const float* __restrict__ w1,
    const float* __restrict__ gamma, const float* __restrict__ beta,
    const float* __restrict__ mean, const float* __restrict__ var,
    const float* __restrict__ cw, const float* __restrict__ cb,
    float* __restrict__ out)
{
    __shared__ __align__(16) unsigned char smem[31760];
    __fp16* bufA = (__fp16*)smem;
    __fp16* lxh  = (__fp16*)smem;
    __fp16* lmid = (__fp16*)(smem + 9216);
    float*  lw2  = (float*)(smem + 18432);

    const int t = threadIdx.x;
    // ---- bijective XCD chunking: 196 = 4*25 + 4*24; wg ordered (b, tile)
    const int id  = blockIdx.x;
    const int xcd = id & 7, lid = id >> 3;
    const int wg  = (xcd < 4 ? xcd * 25 : 100 + (xcd - 4) * 24) + lid;
    const int b    = wg / 49;
    const int tile = wg % 49;
    const int th = tile / 7, tw = tile % 7;
    const int h0 = th * 8, w0 = tw * 8;
    const int lane = t & 63, wvid = t >> 6;
    const int mrow = lane & 15, quad = lane >> 4;

    // ---------------- conv1: 64px x 64o, K=256 in 4 pipelined chunks -------
    const int orow = wvid * 16 + mrow;
    const float s1 = gamma[orow] * rsqrtf(var[orow] + EPS);

    half8t A[4][2];
#pragma unroll
    for (int ch = 0; ch < 4; ++ch)
#pragma unroll
        for (int h = 0; h < 2; ++h) {
            const float* src = &w1[orow * 256 + ch * 64 + h * 32 + quad * 8];
            A[ch][h] = pack8(*(const float4*)src, *(const float4*)(src + 4), s1);
        }

    const int c2 = t & 31, px8 = t >> 5;
    const float* xbase = &x[(size_t)(b * 256 + 2 * c2) * 3136 + (h0 + px8) * 56 + w0];

    float4 ca0 = *(const float4*)xbase;
    float4 ca1 = *(const float4*)(xbase + 4);
    float4 cb0 = *(const float4*)(xbase + 3136);
    float4 cb1 = *(const float4*)(xbase + 3140);

    floatx4 acc1[4] = {};
#pragma unroll
    for (int ch = 0; ch < 4; ++ch) {
        float4 na0, na1, nb0, nb1;
        if (ch < 3) {
            const float* rn = xbase + (size_t)(ch + 1) * 64 * 3136;
            na0 = *(const float4*)rn;
            na1 = *(const float4*)(rn + 4);
            nb0 = *(const float4*)(rn + 3136);
            nb1 = *(const float4*)(rn + 3140);
        }
        float fa[8], fb[8];
        fa[0]=ca0.x; fa[1]=ca0.y; fa[2]=ca0.z; fa[3]=ca0.w;
        fa[4]=ca1.x; fa[5]=ca1.y; fa[6]=ca1.z; fa[7]=ca1.w;
        fb[0]=cb0.x; fb[1]=cb0.y; fb[2]=cb0.z; fb[3]=cb0.w;
        fb[4]=cb1.x; fb[5]=cb1.y; fb[6]=cb1.z; fb[7]=cb1.w;
#pragma unroll
        for (int j = 0; j < 8; ++j) {
            half2t q = __builtin_amdgcn_cvt_pkrtz(fa[j], fb[j]);
            *(half2t*)&bufA[(px8 * 8 + j) * 72 + 2 * c2] = q;
        }
        __syncthreads();
#pragma unroll
        for (int pt = 0; pt < 4; ++pt) {
            half8t bf0 = *(const half8t*)&bufA[(pt * 16 + mrow) * 72 + quad * 8];
            half8t bf1 = *(const half8t*)&bufA[(pt * 16 + mrow) * 72 + quad * 8 + 32];
            acc1[pt] = __builtin_amdgcn_mfma_f32_16x16x32_f16(A[ch][0], bf0, acc1[pt], 0, 0, 0);
            acc1[pt] = __builtin_amdgcn_mfma_f32_16x16x32_f16(A[ch][1], bf1, acc1[pt], 0, 0, 0);
        }
        __syncthreads();
        ca0 = na0; ca1 = na1; cb0 = nb0; cb1 = nb1;
    }

    // conv1 epilogue: bias + relu -> lmid [px][c] f16 (stride 72)
    {
        float bb[4];
#pragma unroll
        for (int i = 0; i < 4; ++i) {
            int o = wvid * 16 + quad * 4 + i;
            float so = gamma[o] * rsqrtf(var[o] + EPS);
            bb[i] = beta[o] - mean[o] * so;
        }
#pragma unroll
        for (int pt = 0; pt < 4; ++pt)
#pragma unroll
            for (int i = 0; i < 4; ++i) {
                float v = fmaxf(acc1[pt][i] + bb[i], 0.f);
                lmid[(pt * 16 + mrow) * 72 + wvid * 16 + quad * 4 + i] = (__fp16)v;
            }
    }
    __syncthreads();   // lmid ready; bufA dead -> lxh region free

    // ---- prefetch for g = 0: halo regs + cw regs ----
    const int krow = wvid * 16 + mrow;
    float4 rv4[4];
    int    rslot[4];
#pragma unroll
    for (int i = 0; i < 4; ++i) {
        int s = t + i * 256;
        rslot[i] = s;
        float4 v = make_float4(0.f, 0.f, 0.f, 0.f);
        if (s < 896) {
            int chh = s / 56, r = s % 56;
            int row = r >> 2, q = r & 3;
            int gh = h0 + row - 3;
            int gwb = w0 - 4 + q * 4;
            bool ok = (gh >= 0) & (gh < 56) & (gwb >= 0) & (gwb <= 52);
            int ghc = min(max(gh, 0), 55);
            int gwc = min(max(gwb, 0), 52);
            float4 ld = *(const float4*)&x[(size_t)(b * 256 + chh) * 3136 +
                                           ghc * 56 + gwc];
            if (ok) v = ld;
        }
        rv4[i] = v;
    }
    float4 rcw0 = make_float4(0,0,0,0), rcw1 = rcw0, rcw2 = rcw0, rcw3 = rcw0;
    if (krow < 49) {
        const float* src = &cw[(size_t)krow * 64 + quad * 8];
        rcw0 = *(const float4*)src;       rcw1 = *(const float4*)(src + 4);
        rcw2 = *(const float4*)(src + 32); rcw3 = *(const float4*)(src + 36);
    }

    // ---------------- per-group loop: GEMM -> halo -> apply ----------------
#pragma unroll 1
    for (int g = 0; g < 16; ++g) {
        // A-frags from prefetched cw regs
        half8t a0 = pack8(rcw0, rcw1, 1.f);
        half8t a1 = pack8(rcw2, rcw3, 1.f);
        if (krow >= 49) { a0 = half8t{}; a1 = half8t{}; }

        // GEMM: D[49 ko x 64 px] = W_g[49 x 64c] * M[64c x 64px]
        {
            float bias[4];
            int   kor[4];
#pragma unroll
            for (int i = 0; i < 4; ++i) {
                kor[i]  = wvid * 16 + quad * 4 + i;
                bias[i] = (kor[i] < 49) ? cb[g * 49 + kor[i]] : 0.f;
            }
#pragma unroll
            for (int pt = 0; pt < 4; ++pt) {
                half8t b0 = *(const half8t*)&lmid[(pt * 16 + mrow) * 72 + quad * 8];
                half8t b1 = *(const half8t*)&lmid[(pt * 16 + mrow) * 72 + quad * 8 + 32];
                floatx4 acc = {0.f, 0.f, 0.f, 0.f};
                acc = __builtin_amdgcn_mfma_f32_16x16x32_f16(a0, b0, acc, 0, 0, 0);
                acc = __builtin_amdgcn_mfma_f32_16x16x32_f16(a1, b1, acc, 0, 0, 0);
#pragma unroll
                for (int i = 0; i < 4; ++i)
                    if (kor[i] < 49)
                        lw2[kor[i] * 68 + pt * 16 + mrow] = acc[i] + bias[i];
            }
        }

        // halo regs -> lxh f16 [ch][row][20] (ch stride 280 halves)
#pragma unroll
        for (int i = 0; i < 4; ++i) {
            int s = rslot[i];
            if (s < 896) {
                int chh = s / 56, r = s % 56;
                int row = r >> 2, q = r & 3;
                half2t p0 = __builtin_amdgcn_cvt_pkrtz(rv4[i].x, rv4[i].y);
                half2t p1 = __builtin_amdgcn_cvt_pkrtz(rv4[i].z, rv4[i].w);
                half4t h; h[0] = p0[0]; h[1] = p0[1]; h[2] = p1[0]; h[3] = p1[1];
                *(half4t*)&lxh[chh * 280 + row * 20 + q * 4] = h;
            }
        }

        // prefetch next group's halo + cw during this apply
        if (g < 15) {
#pragma unroll
            for (int i = 0; i < 4; ++i) {
                int s = rslot[i];
                float4 v = make_float4(0.f, 0.f, 0.f, 0.f);
                if (s < 896) {
                    int chh = s / 56, r = s % 56;
                    int row = r >> 2, q = r & 3;
                    int gh = h0 + row - 3;
                    int gwb = w0 - 4 + q * 4;
                    bool ok = (gh >= 0) & (gh < 56) & (gwb >= 0) & (gwb <= 52);
                    int ghc = min(max(gh, 0), 55);
                    int gwc = min(max(gwb, 0), 52);
                    float4 ld = *(const float4*)&x[(size_t)(b * 256 + (g + 1) * 16 + chh) * 3136 +
                                                   ghc * 56 + gwc];
                    if (ok) v = ld;
                }
                rv4[i] = v;
            }
            if (krow < 49) {
                const float* src = &cw[(size_t)((g + 1) * 49 + krow) * 64 + quad * 8];
                rcw0 = *(const float4*)src;        rcw1 = *(const float4*)(src + 4);
                rcw2 = *(const float4*)(src + 32); rcw3 = *(const float4*)(src + 36);
            }
        }
        __syncthreads();   // lw2 + lxh ready

        // apply: thread = (cc = t>>4 ch, 4 px); f16 x, f32 weights/accum
        {
            const int cc = t >> 4, pxt = t & 15;
            const int sh = pxt >> 1, sw4 = (pxt & 1) * 4;
            float a0f = 0.f, a1f = 0.f, a2f = 0.f, a3f = 0.f;
#pragma unroll
            for (int kh = 0; kh < 7; ++kh) {
                const int rbh = cc * 280 + (sh + kh) * 20 + sw4;
                half4t f0 = *(const half4t*)&lxh[rbh];
                half4t f1 = *(const half4t*)&lxh[rbh + 4];
                half4t f2 = *(const half4t*)&lxh[rbh + 8];
                float xw[12];
#pragma unroll
                for (int j = 0; j < 4; ++j) {
                    xw[j]     = (float)f0[j];
                    xw[j + 4] = (float)f1[j];
                    xw[j + 8] = (float)f2[j];
                }
#pragma unroll
                for (int kw = 0; kw < 7; ++kw) {
                    const float4 wv = *(const float4*)&lw2[(kh * 7 + kw) * 68 + pxt * 4];
                    a0f = fmaf(wv.x, xw[kw + 1], a0f);
                    a1f = fmaf(wv.y, xw[kw + 2], a1f);
                    a2f = fmaf(wv.z, xw[kw + 3], a2f);
                    a3f = fmaf(wv.w, xw[kw + 4], a3f);
                }
            }
            *(float4*)&out[(size_t)(b * 256 + g * 16 + cc) * 3136 +
                           (h0 + sh) * 56 + w0 + sw4] =
                make_float4(a0f, a1f, a2f, a3f);
        }
        __syncthreads();   // lxh/lw2 consumed; next g may overwrite
    }
}

extern "C" void kernel_launch(void* const* d_in, const int* in_sizes, int n_in,
                              void* d_out, int out_size, void* d_ws, size_t ws_size,
                              hipStream_t stream) {
    const float* x     = (const float*)d_in[0];
    const float* w1    = (const float*)d_in[1];
    const float* gamma = (const float*)d_in[2];
    const float* beta  = (const float*)d_in[3];
    const float* mean  = (const float*)d_in[4];
    const float* var   = (const float*)d_in[5];
    const float* cw    = (const float*)d_in[6];
    const float* cb    = (const float*)d_in[7];
    float* out = (float*)d_out;

    (void)d_ws; (void)ws_size;

    k_fused<<<dim3(196), 256, 0, stream>>>(x, w1, gamma, beta, mean, var,
                                           cw, cb, out);
}

// Round 9
// 107.193 us; speedup vs baseline: 1.0707x; 1.0707x over previous
//
#include <hip/hip_runtime.h>

// Involution: B=4, C=256, H=W=56, K=7, GC=16 -> G=16, Cr=64, K2=49
// R9: SINGLE kernel, grid 196 = (49 tiles x 4 b), 512 threads (8 waves).
//     conv1 computed ONCE per tile, split across all 8 waves (each wave:
//     one 16-o strip x one 32-px half). Group loop: 8 iterations, TWO
//     groups concurrently (wave-set hs = wvid>>2 owns g = 2i+hs) with
//     disjoint lw2/lxh buffers -> serial chain halves, 2 streams/barrier.
//     halo(g+2)+cw(g+2) prefetched into regs during apply(g).
//     Bijective XCD chunking over wg=(b,tile).
// LDS map (bytes), total 54048:
//   [0, 9216)       bufA [64px][72] f16  - conv1 staging
//   [0, 8960)       lxh0 [16ch][14][20] f16 - overlays bufA after conv1
//   [9216, 18432)   lmid [64px][72] f16  - conv1 out tile (read-only shared)
//   [18432, 31760)  lw2[0] [49][68] f32  - set-0 weights
//   [31760, 45088)  lw2[1] [49][68] f32  - set-1 weights
//   [45088, 54048)  lxh1 [16ch][14][20] f16 - set-1 halo
// ws unused.

#define EPS 1e-5f

typedef __fp16 half2t __attribute__((ext_vector_type(2)));
typedef __fp16 half4t __attribute__((ext_vector_type(4)));
typedef __fp16 half8t __attribute__((ext_vector_type(8)));
typedef float floatx4 __attribute__((ext_vector_type(4)));

__device__ inline half8t pack8(float4 u0, float4 u1, float s) {
    half8t a;
    half2t q;
    q = __builtin_amdgcn_cvt_pkrtz(u0.x * s, u0.y * s); a[0] = q[0]; a[1] = q[1];
    q = __builtin_amdgcn_cvt_pkrtz(u0.z * s, u0.w * s); a[2] = q[0]; a[3] = q[1];
    q = __builtin_amdgcn_cvt_pkrtz(u1.x * s, u1.y * s); a[4] = q[0]; a[5] = q[1];
    q = __builtin_amdgcn_cvt_pkrtz(u1.z * s, u1.w * s); a[6] = q[0]; a[7] = q[1];
    return a;
}

__global__ __launch_bounds__(512, 2) void k_fused(
    const float* __restrict__ x, const float* __restrict__ w1,
    const float* __restrict__ gamma, const float* __restrict__ beta,
    const float* __restrict__ mean, const float* __restrict__ var,
    const float* __restrict__ cw, const float* __restrict__ cb,
    float* __restrict__ out)
{
    __shared__ __align__(16) unsigned char smem[54048];
    __fp16* bufA = (__fp16*)smem;
    __fp16* lmid = (__fp16*)(smem + 9216);

    const int t = threadIdx.x;
    // ---- bijective XCD chunking: 196 = 4*25 + 4*24; wg ordered (b, tile)
    const int id  = blockIdx.x;
    const int xcd = id & 7, lid = id >> 3;
    const int wg  = (xcd < 4 ? xcd * 25 : 100 + (xcd - 4) * 24) + lid;
    const int b    = wg / 49;
    const int tile = wg % 49;
    const int th = tile / 7, tw = tile % 7;
    const int h0 = th * 8, w0 = tw * 8;
    const int lane = t & 63, wvid = t >> 6;
    const int mrow = lane & 15, quad = lane >> 4;

    // ---------------- conv1: 8-wave split (o-strip ow, px-half ph) ---------
    const int ow = wvid & 3, ph = wvid >> 2;
    const int orow = ow * 16 + mrow;
    const float s1 = gamma[orow] * rsqrtf(var[orow] + EPS);

    half8t A[4][2];
#pragma unroll
    for (int ch = 0; ch < 4; ++ch)
#pragma unroll
        for (int h = 0; h < 2; ++h) {
            const float* src = &w1[orow * 256 + ch * 64 + h * 32 + quad * 8];
            A[ch][h] = pack8(*(const float4*)src, *(const float4*)(src + 4), s1);
        }

    // staging map: ch-pair c2 0..31, pq 0..15 -> row = pq>>1, col-half ch4
    const int c2 = t & 31, pq = t >> 5;
    const int srow = pq >> 1, ch4 = (pq & 1) * 4;
    const float* xbase = &x[(size_t)(b * 256 + 2 * c2) * 3136 +
                            (h0 + srow) * 56 + w0 + ch4];

    float4 ca = *(const float4*)xbase;
    float4 cbv = *(const float4*)(xbase + 3136);

    floatx4 acc1[2] = {};
#pragma unroll
    for (int ch = 0; ch < 4; ++ch) {
        float4 na, nb;
        if (ch < 3) {
            const float* rn = xbase + (size_t)(ch + 1) * 64 * 3136;
            na = *(const float4*)rn;
            nb = *(const float4*)(rn + 3136);
        }
        const float* fa = (const float*)&ca;
        const float* fb = (const float*)&cbv;
#pragma unroll
        for (int j = 0; j < 4; ++j) {
            half2t q = __builtin_amdgcn_cvt_pkrtz(fa[j], fb[j]);
            *(half2t*)&bufA[(srow * 8 + ch4 + j) * 72 + 2 * c2] = q;
        }
        __syncthreads();
#pragma unroll
        for (int p2 = 0; p2 < 2; ++p2) {
            int pt = ph * 2 + p2;
            half8t bf0 = *(const half8t*)&bufA[(pt * 16 + mrow) * 72 + quad * 8];
            half8t bf1 = *(const half8t*)&bufA[(pt * 16 + mrow) * 72 + quad * 8 + 32];
            acc1[p2] = __builtin_amdgcn_mfma_f32_16x16x32_f16(A[ch][0], bf0, acc1[p2], 0, 0, 0);
            acc1[p2] = __builtin_amdgcn_mfma_f32_16x16x32_f16(A[ch][1], bf1, acc1[p2], 0, 0, 0);
        }
        __syncthreads();
        ca = na; cbv = nb;
    }

    // conv1 epilogue: bias + relu -> lmid [px][c] f16 (stride 72)
    {
        float bb[4];
#pragma unroll
        for (int i = 0; i < 4; ++i) {
            int o = ow * 16 + quad * 4 + i;
            float so = gamma[o] * rsqrtf(var[o] + EPS);
            bb[i] = beta[o] - mean[o] * so;
        }
#pragma unroll
        for (int p2 = 0; p2 < 2; ++p2)
#pragma unroll
            for (int i = 0; i < 4; ++i) {
                float v = fmaxf(acc1[p2][i] + bb[i], 0.f);
                lmid[((ph * 2 + p2) * 16 + mrow) * 72 + ow * 16 + quad * 4 + i] = (__fp16)v;
            }
    }
    __syncthreads();   // lmid ready; bufA dead -> lxh0 region free

    // ---------------- group loop: 2 concurrent wave-sets -------------------
    const int hs = wvid >> 2;          // wave-set: handles g = 2*gi + hs
    const int wl = wvid & 3;           // local wave in set
    const int tl = t & 255;            // local thread in set
    __fp16* myxh = (hs == 0) ? (__fp16*)smem : (__fp16*)(smem + 45088);
    float*  mylw = (float*)(smem + 18432 + hs * 13328);
    const int krow = wl * 16 + mrow;

    // prefetch g = hs: halo + cw
    float4 rv4[4];
    int    rslot[4];
#pragma unroll
    for (int i = 0; i < 4; ++i) {
        int s = tl + i * 256;
        rslot[i] = s;
        float4 v = make_float4(0.f, 0.f, 0.f, 0.f);
        if (s < 896) {
            int chh = s / 56, r = s % 56;
            int row = r >> 2, q = r & 3;
            int gh = h0 + row - 3;
            int gwb = w0 - 4 + q * 4;
            bool ok = (gh >= 0) & (gh < 56) & (gwb >= 0) & (gwb <= 52);
            int ghc = min(max(gh, 0), 55);
            int gwc = min(max(gwb, 0), 52);
            float4 ld = *(const float4*)&x[(size_t)(b * 256 + hs * 16 + chh) * 3136 +
                                           ghc * 56 + gwc];
            if (ok) v = ld;
        }
        rv4[i] = v;
    }
    float4 rcw0 = make_float4(0,0,0,0), rcw1 = rcw0, rcw2 = rcw0, rcw3 = rcw0;
    if (krow < 49) {
        const float* src = &cw[(size_t)(hs * 49 + krow) * 64 + quad * 8];
        rcw0 = *(const float4*)src;        rcw1 = *(const float4*)(src + 4);
        rcw2 = *(const float4*)(src + 32); rcw3 = *(const float4*)(src + 36);
    }

#pragma unroll 1
    for (int gi = 0; gi < 8; ++gi) {
        const int g = gi * 2 + hs;

        half8t a0 = pack8(rcw0, rcw1, 1.f);
        half8t a1 = pack8(rcw2, rcw3, 1.f);
        if (krow >= 49) { a0 = half8t{}; a1 = half8t{}; }

        // GEMM: D[49 ko x 64 px] = W_g[49 x 64c] * M[64c x 64px] (per set)
        {
            float bias[4];
            int   kor[4];
#pragma unroll
            for (int i = 0; i < 4; ++i) {
                kor[i]  = wl * 16 + quad * 4 + i;
                bias[i] = (kor[i] < 49) ? cb[g * 49 + kor[i]] : 0.f;
            }
#pragma unroll
            for (int pt = 0; pt < 4; ++pt) {
                half8t b0 = *(const half8t*)&lmid[(pt * 16 + mrow) * 72 + quad * 8];
                half8t b1 = *(const half8t*)&lmid[(pt * 16 + mrow) * 72 + quad * 8 + 32];
                floatx4 acc = {0.f, 0.f, 0.f, 0.f};
                acc = __builtin_amdgcn_mfma_f32_16x16x32_f16(a0, b0, acc, 0, 0, 0);
                acc = __builtin_amdgcn_mfma_f32_16x16x32_f16(a1, b1, acc, 0, 0, 0);
#pragma unroll
                for (int i = 0; i < 4; ++i)
                    if (kor[i] < 49)
                        mylw[kor[i] * 68 + pt * 16 + mrow] = acc[i] + bias[i];
            }
        }

        // halo regs -> myxh f16 [ch][row][20] (ch stride 280 halves)
#pragma unroll
        for (int i = 0; i < 4; ++i) {
            int s = rslot[i];
            if (s < 896) {
                int chh = s / 56, r = s % 56;
                int row = r >> 2, q = r & 3;
                half2t p0 = __builtin_amdgcn_cvt_pkrtz(rv4[i].x, rv4[i].y);
                half2t p1 = __builtin_amdgcn_cvt_pkrtz(rv4[i].z, rv4[i].w);
                half4t hv; hv[0] = p0[0]; hv[1] = p0[1]; hv[2] = p1[0]; hv[3] = p1[1];
                *(half4t*)&myxh[chh * 280 + row * 20 + q * 4] = hv;
            }
        }

        // prefetch next group's halo + cw (g+2)
        if (gi < 7) {
#pragma unroll
            for (int i = 0; i < 4; ++i) {
                int s = rslot[i];
                float4 v = make_float4(0.f, 0.f, 0.f, 0.f);
                if (s < 896) {
                    int chh = s / 56, r = s % 56;
                    int row = r >> 2, q = r & 3;
                    int gh = h0 + row - 3;
                    int gwb = w0 - 4 + q * 4;
                    bool ok = (gh >= 0) & (gh < 56) & (gwb >= 0) & (gwb <= 52);
                    int ghc = min(max(gh, 0), 55);
                    int gwc = min(max(gwb, 0), 52);
                    float4 ld = *(const float4*)&x[(size_t)(b * 256 + (g + 2) * 16 + chh) * 3136 +
                                                   ghc * 56 + gwc];
                    if (ok) v = ld;
                }
                rv4[i] = v;
            }
            if (krow < 49) {
                const float* src = &cw[(size_t)((g + 2) * 49 + krow) * 64 + quad * 8];
                rcw0 = *(const float4*)src;        rcw1 = *(const float4*)(src + 4);
                rcw2 = *(const float4*)(src + 32); rcw3 = *(const float4*)(src + 36);
            }
        }
        __syncthreads();   // lw2 + lxh ready (both sets)

        // apply: per set, thread = (cc = tl>>4 ch, 4 px); f16 x, f32 accum
        {
            const int cc = tl >> 4, pxt = tl & 15;
            const int sh = pxt >> 1, sw4 = (pxt & 1) * 4;
            float a0f = 0.f, a1f = 0.f, a2f = 0.f, a3f = 0.f;
#pragma unroll
            for (int kh = 0; kh < 7; ++kh) {
                const int rbh = cc * 280 + (sh + kh) * 20 + sw4;
                half4t f0 = *(const half4t*)&myxh[rbh];
                half4t f1 = *(const half4t*)&myxh[rbh + 4];
                half4t f2 = *(const half4t*)&myxh[rbh + 8];
                float xw[12];
#pragma unroll
                for (int j = 0; j < 4; ++j) {
                    xw[j]     = (float)f0[j];
                    xw[j + 4] = (float)f1[j];
                    xw[j + 8] = (float)f2[j];
                }
#pragma unroll
                for (int kw = 0; kw < 7; ++kw) {
                    const float4 wv = *(const float4*)&mylw[(kh * 7 + kw) * 68 + pxt * 4];
                    a0f = fmaf(wv.x, xw[kw + 1], a0f);
                    a1f = fmaf(wv.y, xw[kw + 2], a1f);
                    a2f = fmaf(wv.z, xw[kw + 3], a2f);
                    a3f = fmaf(wv.w, xw[kw + 4], a3f);
                }
            }
            *(float4*)&out[(size_t)(b * 256 + g * 16 + cc) * 3136 +
                           (h0 + sh) * 56 + w0 + sw4] =
                make_float4(a0f, a1f, a2f, a3f);
        }
        __syncthreads();   // buffers consumed; next gi may overwrite
    }
}

extern "C" void kernel_launch(void* const* d_in, const int* in_sizes, int n_in,
                              void* d_out, int out_size, void* d_ws, size_t ws_size,
                              hipStream_t stream) {
    const float* x     = (const float*)d_in[0];
    const float* w1    = (const float*)d_in[1];
    const float* gamma = (const float*)d_in[2];
    const float* beta  = (const float*)d_in[3];
    const float* mean  = (const float*)d_in[4];
    const float* var   = (const float*)d_in[5];
    const float* cw    = (const float*)d_in[6];
    const float* cb    = (const float*)d_in[7];
    float* out = (float*)d_out;

    (void)d_ws; (void)ws_size;

    k_fused<<<dim3(196), 512, 0, stream>>>(x, w1, gamma, beta, mean, var,
                                           cw, cb, out);
}